// Round 4
// baseline (1271.359 us; speedup 1.0000x reference)
//
#include <hip/hip_runtime.h>

#define F_IN  128
#define F_HID 8
#define F_OUT 16

// edge_index arrives as int32 [2][E] (harness downcasts int64 inputs).
// Algebra: agg[i] = dis[i] * ( sum_{s in N(i)} g[s] + g[i] ),  g = h * dis.
// CSR stores src only (4B/edge); all normalization folded into g and epilogue.

__global__ void init_cnt(int* __restrict__ cnt, int* __restrict__ cursor, int n) {
    int i = blockIdx.x * blockDim.x + threadIdx.x;
    if (i < n) cnt[i] = 0;
    if (i == 0) *cursor = 0;
}

__global__ void count_dst(const int* __restrict__ ei, int* __restrict__ cnt, int E) {
    int t = blockIdx.x * blockDim.x + threadIdx.x;
    int base = t * 4;
    if (base + 3 < E) {
        int4 v = *(const int4*)(ei + E + base);
        atomicAdd(&cnt[v.x], 1);
        atomicAdd(&cnt[v.y], 1);
        atomicAdd(&cnt[v.z], 1);
        atomicAdd(&cnt[v.w], 1);
    } else if (base < E) {
        for (int k = base; k < E; k++) atomicAdd(&cnt[ei[E + k]], 1);
    }
}

// deg = cnt + 1 (self-loop); dis = rsqrt(deg); contiguous (unordered) row ranges
__global__ void calc_offsets(const int* __restrict__ cnt, float* __restrict__ dis,
                             int* __restrict__ row_start, int* __restrict__ row_cur,
                             int* __restrict__ cursor, int n) {
    int i = blockIdx.x * blockDim.x + threadIdx.x;
    if (i >= n) return;
    int c = cnt[i];
    dis[i] = rsqrtf((float)(c + 1));
    int rs = atomicAdd(cursor, c);
    row_start[i] = rs;
    row_cur[i]   = rs;
}

__global__ __launch_bounds__(256) void fill_csr(const int* __restrict__ ei,
                                                int* __restrict__ row_cur,
                                                int* __restrict__ csr, int E) {
    int e = blockIdx.x * blockDim.x + threadIdx.x;
    if (e >= E) return;
    int s = ei[e];
    int d = ei[E + e];
    int pos = atomicAdd(&row_cur[d], 1);
    csr[pos] = s;
}

// ---------------- layer-1 GEMM: g1 = (x @ W1) * dis ----------------
__global__ __launch_bounds__(256) void gemm1(const float* __restrict__ x,
                                             const float* __restrict__ W1,
                                             const float* __restrict__ dis,
                                             float* __restrict__ g1, int n) {
    __shared__ float w[F_IN * F_HID];  // 4 KB
    for (int i = threadIdx.x; i < F_IN * F_HID; i += blockDim.x) w[i] = W1[i];
    __syncthreads();
    int node = blockIdx.x * blockDim.x + threadIdx.x;
    if (node >= n) return;
    const float4* xr = (const float4*)(x + (size_t)node * F_IN);
    float acc[F_HID];
#pragma unroll
    for (int f = 0; f < F_HID; f++) acc[f] = 0.0f;
#pragma unroll
    for (int j = 0; j < F_IN / 4; j++) {
        float4 v = xr[j];
        const float* wr = &w[j * 4 * F_HID];
#pragma unroll
        for (int f = 0; f < F_HID; f++)
            acc[f] += v.x * wr[f] + v.y * wr[F_HID + f] + v.z * wr[2 * F_HID + f] + v.w * wr[3 * F_HID + f];
    }
    float d = dis[node];
    float4* gp = (float4*)(g1 + (size_t)node * F_HID);
    gp[0] = make_float4(acc[0] * d, acc[1] * d, acc[2] * d, acc[3] * d);
    gp[1] = make_float4(acc[4] * d, acc[5] * d, acc[6] * d, acc[7] * d);
}

// ---------------- aggregation: agg[i] = dis[i] * (sum g[src] + g[i]); 8 lanes/node ----------------
__global__ __launch_bounds__(256) void aggregate(const int* __restrict__ csr,
                                                 const int* __restrict__ row_start,
                                                 const int* __restrict__ cnt,
                                                 const float* __restrict__ dis,
                                                 const float* __restrict__ g,
                                                 float* __restrict__ agg, int n) {
    int t = blockIdx.x * blockDim.x + threadIdx.x;
    int node = t >> 3;
    int f = t & 7;
    if (node >= n) return;
    int beg = row_start[node];
    int c   = cnt[node];
    float acc = g[(size_t)node * F_HID + f];        // self-loop
    for (int j = 0; j < c; j++) {
        int s = csr[beg + j];                       // uniform across the 8-lane group
        acc += g[(size_t)s * F_HID + f];
    }
    agg[(size_t)node * F_HID + f] = acc * dis[node];
}

// ---------------- g2 = relu(agg1 + b1) * dis ----------------
__global__ __launch_bounds__(256) void relu_init(const float* __restrict__ b1,
                                                 const float* __restrict__ dis,
                                                 const float* __restrict__ agg1,
                                                 float* __restrict__ g2, int n) {
    int i = blockIdx.x * blockDim.x + threadIdx.x;
    if (i >= n) return;
    float d = dis[i];
    const float4* a = (const float4*)(agg1 + (size_t)i * F_HID);
    float4 lo = a[0], hi = a[1];
    lo.x = fmaxf(lo.x + b1[0], 0.0f) * d;
    lo.y = fmaxf(lo.y + b1[1], 0.0f) * d;
    lo.z = fmaxf(lo.z + b1[2], 0.0f) * d;
    lo.w = fmaxf(lo.w + b1[3], 0.0f) * d;
    hi.x = fmaxf(hi.x + b1[4], 0.0f) * d;
    hi.y = fmaxf(hi.y + b1[5], 0.0f) * d;
    hi.z = fmaxf(hi.z + b1[6], 0.0f) * d;
    hi.w = fmaxf(hi.w + b1[7], 0.0f) * d;
    float4* o = (float4*)(g2 + (size_t)i * F_HID);
    o[0] = lo; o[1] = hi;
}

// ---------------- out = agg2 @ W2 + b2 ----------------
__global__ __launch_bounds__(256) void gemm2(const float* __restrict__ agg2,
                                             const float* __restrict__ W2,
                                             const float* __restrict__ b2,
                                             float* __restrict__ out, int n) {
    __shared__ float w[F_HID * F_OUT];
    __shared__ float bb[F_OUT];
    if (threadIdx.x < F_HID * F_OUT) w[threadIdx.x] = W2[threadIdx.x];
    if (threadIdx.x < F_OUT) bb[threadIdx.x] = b2[threadIdx.x];
    __syncthreads();
    int node = blockIdx.x * blockDim.x + threadIdx.x;
    if (node >= n) return;
    const float4* ap = (const float4*)(agg2 + (size_t)node * F_HID);
    float4 lo = ap[0], hi = ap[1];
    float a[F_HID] = {lo.x, lo.y, lo.z, lo.w, hi.x, hi.y, hi.z, hi.w};
    float o[F_OUT];
#pragma unroll
    for (int f = 0; f < F_OUT; f++) o[f] = bb[f];
#pragma unroll
    for (int k = 0; k < F_HID; k++) {
#pragma unroll
        for (int f = 0; f < F_OUT; f++) o[f] += a[k] * w[k * F_OUT + f];
    }
    float4* op = (float4*)(out + (size_t)node * F_OUT);
    op[0] = make_float4(o[0], o[1], o[2], o[3]);
    op[1] = make_float4(o[4], o[5], o[6], o[7]);
    op[2] = make_float4(o[8], o[9], o[10], o[11]);
    op[3] = make_float4(o[12], o[13], o[14], o[15]);
}

extern "C" void kernel_launch(void* const* d_in, const int* in_sizes, int n_in,
                              void* d_out, int out_size, void* d_ws, size_t ws_size,
                              hipStream_t stream) {
    const float* x  = (const float*)d_in[0];
    const int*   ei = (const int*)d_in[1];
    const float* W1 = (const float*)d_in[2];
    const float* b1 = (const float*)d_in[3];
    const float* W2 = (const float*)d_in[4];
    const float* b2 = (const float*)d_in[5];
    float* out = (float*)d_out;

    const int N = in_sizes[0] / F_IN;
    const int E = in_sizes[1] / 2;

    // ws layout (floats/ints, 4B units):
    // csr[E] | dis[N] | bufA[8N] (g1/g2) | bufB[8N] (agg1/agg2) | cnt[N] | row_start[N] | row_cur[N] | cursor[1]
    int*   csr       = (int*)d_ws;
    float* dis       = (float*)csr + E;
    float* bufA      = dis + N;
    float* bufB      = bufA + (size_t)N * F_HID;
    int*   cnt       = (int*)(bufB + (size_t)N * F_HID);
    int*   row_start = cnt + N;
    int*   row_cur   = row_start + N;
    int*   cursor    = row_cur + N;

    const int BT = 256;
    dim3 blkN((N + BT - 1) / BT), blkE((E + BT - 1) / BT), thr(BT);
    dim3 blkE4((E / 4 + BT) / BT);
    dim3 blkA(((size_t)N * F_HID + BT - 1) / BT);

    init_cnt    <<<blkN,  thr, 0, stream>>>(cnt, cursor, N);
    count_dst   <<<blkE4, thr, 0, stream>>>(ei, cnt, E);
    calc_offsets<<<blkN,  thr, 0, stream>>>(cnt, dis, row_start, row_cur, cursor, N);
    fill_csr    <<<blkE,  thr, 0, stream>>>(ei, row_cur, csr, E);
    gemm1       <<<blkN,  thr, 0, stream>>>(x, W1, dis, bufA, N);
    aggregate   <<<blkA,  thr, 0, stream>>>(csr, row_start, cnt, dis, bufA, bufB, N);
    relu_init   <<<blkN,  thr, 0, stream>>>(b1, dis, bufB, bufA, N);
    aggregate   <<<blkA,  thr, 0, stream>>>(csr, row_start, cnt, dis, bufA, bufB, N);
    gemm2       <<<blkN,  thr, 0, stream>>>(bufB, W2, b2, out, N);
}